// Round 14
// baseline (4768.155 us; speedup 1.0000x reference)
//
#include <hip/hip_runtime.h>

// Bidirectional GRU, persistent-kernel. Round 14.
// Real work (blocks 0-63): r13 VERBATIM (equal-best, 4414us; 2-deep pipelined
// fan-in-16 poll, per-wave h-drain, monotonic flags, lgkm barriers, post-flag
// prefetch). ROUND 14 MECHANISM (one change): MEMORY-STREAMING heaters.
// r12 killed only the SCLK half of the clock hypothesis (VALU heaters, 75%
// VALUBusy, null). FCLK/UCLK - the fabric/LLC clocks on the comm-RTT path -
// respond to MEMORY traffic, and 210 GB/s looks idle to that governor.
// Heater blocks 64-255 grid-stride-read x (67MB, LLC-resident after sweep 1:
// pure fabric+LLC load on exactly the comm path, no HBM queue poisoning).
// Liveness (r12-proven): done-counter exit + hard sweep budget -> no hang.

#define T_LEN 1024
#define B_SZ  32
#define D_SZ  512
#define H_SZ  512
#define NWG_DIR 32
#define JW 16
#define NTHR 512

typedef __attribute__((ext_vector_type(8))) _Float16 half8;
typedef __attribute__((ext_vector_type(4))) float f32x4;
typedef __attribute__((ext_vector_type(4))) int int4v;

__device__ __forceinline__ _Float16 f2h(float f) { return (_Float16)f; }
__device__ __forceinline__ float sigm_f(float v) {
  return __builtin_amdgcn_rcpf(1.f + __expf(-v));
}
__device__ __forceinline__ float tanh_f(float v) {
  return 1.f - 2.f * __builtin_amdgcn_rcpf(1.f + __expf(2.f * v));
}
// LDS-only barrier: orders ds ops; does NOT drain vmcnt.
__device__ __forceinline__ void bar_lgkm() {
  asm volatile("s_waitcnt lgkmcnt(0)\ns_barrier" ::: "memory");
}

__global__ __launch_bounds__(NTHR, 2)
void gru2_persistent(const float* __restrict__ x,
                     const float* __restrict__ wih_fw, const float* __restrict__ whh_fw,
                     const float* __restrict__ bih_fw, const float* __restrict__ bhh_fw,
                     const float* __restrict__ wih_bw, const float* __restrict__ whh_bw,
                     const float* __restrict__ bih_bw, const float* __restrict__ bhh_bw,
                     float* __restrict__ out,
                     unsigned* __restrict__ hexu,
                     unsigned* __restrict__ flags,
                     unsigned* __restrict__ done)
{
  __shared__ float Cp[24 * 272];   // 24 C-partial tiles 16x16, +1 col pad
  __shared__ float biasLds[96];
  __shared__ volatile int hdone;   // heater-exit token

  const int bid  = blockIdx.x;
  const int tid  = threadIdx.x;
  const int wave = tid >> 6;
  const int lane = tid & 63;

  // ================= MEMORY-STREAMING HEATERS (blocks 64..255) =============
  if (bid >= 64) {
    if (tid == 0) hdone = 0;
    __syncthreads();
    const int hb = bid - 64;                       // 0..191
    const float4* xv = (const float4*)x;
    const int CHUNK = 21504;                       // float4s per block-sweep
    const int base  = hb * CHUNK;                  // max 4,128,768 < 4,194,304
    float acc0 = 0.f, acc1 = 0.f;
    for (int it = 0; it < (1 << 17); ++it) {       // hard budget backstop
      for (int i = tid; i < CHUNK; i += 2 * NTHR) {
        float4 v0 = xv[base + i];
        float4 v1 = xv[base + i + NTHR];
        acc0 += v0.x + v0.y + v0.z + v0.w;
        acc1 += v1.x + v1.y + v1.z + v1.w;
      }
      if (tid == 0) {
        unsigned d = __hip_atomic_load(done, __ATOMIC_RELAXED,
                                       __HIP_MEMORY_SCOPE_AGENT);
        if (d >= 64u) hdone = 1;
      }
      if (hdone) break;
    }
    asm volatile("" :: "v"(acc0), "v"(acc1));      // no-DCE sink
    return;
  }

  // ================= REAL WORK (blocks 0..63): r13 verbatim ================
  const int dir  = bid >> 5;      // 0 = fw, 1 = bw
  const int g    = bid & 31;      // slice: h-cols [g*16, g*16+16)

  const float* wih = dir ? wih_bw : wih_fw;
  const float* whh = dir ? whh_bw : whh_fw;
  const float* bih = dir ? bih_bw : bih_fw;
  const float* bhh = dir ? bhh_bw : bhh_fw;

  if (tid < 48) {
    int grow = (tid >> 4) * H_SZ + g * JW + (tid & 15);
    biasLds[tid]      = bih[grow];
    biasLds[48 + tid] = bhh[grow];
  }

  const bool isHh = (wave >= 4);
  const int  wv   = wave & 3;
  const int  wm   = wv & 1;       // batch m-tile (16 rows)
  const int  kh   = wv >> 1;      // K half

  // ---- weight B-fragments in registers (layout proven r1-r13) ----
  half8 Bf[3][8];
  {
    const float* W = isHh ? whh : wih;
    #pragma unroll
    for (int gam = 0; gam < 3; ++gam) {
      const int row = gam * H_SZ + g * JW + (lane & 15);
      #pragma unroll
      for (int i = 0; i < 8; ++i) {
        const float* src = W + (size_t)row * D_SZ + (kh * 8 + i) * 32 + ((lane >> 4) << 3);
        float4 v0 = *(const float4*)(src);
        float4 v1 = *(const float4*)(src + 4);
        half8 b;
        b[0]=f2h(v0.x); b[1]=f2h(v0.y); b[2]=f2h(v0.z); b[3]=f2h(v0.w);
        b[4]=f2h(v1.x); b[5]=f2h(v1.y); b[6]=f2h(v1.z); b[7]=f2h(v1.w);
        Bf[gam][i] = b;
      }
    }
  }

  const int arow = wm * 16 + (lane & 15);   // batch row
  const int koff = (lane >> 4) << 3;        // k offset within 32-chunk
  const float* const xwavebase = x + (size_t)arow * T_LEN * D_SZ + kh * 256 + koff;

  // ---- ih prologue: x(t0) into registers
  float4 xn[16];
  if (!isHh) {
    const int t0 = dir ? (T_LEN - 1) : 0;
    const float* base = xwavebase + (size_t)t0 * D_SZ;
    #pragma unroll
    for (int i = 0; i < 8; ++i) {
      xn[2*i]   = *(const float4*)(base + i * 32);
      xn[2*i+1] = *(const float4*)(base + i * 32 + 4);
    }
  }
  __syncthreads();

  float hreg = 0.f;
  const int gb = tid >> 4;       // gate batch row
  const int gj = tid & 15;       // gate col within slice
  float* hlast = out + (size_t)B_SZ * T_LEN * (2 * H_SZ) + (size_t)dir * B_SZ * H_SZ;
  // fan-in-16 poll address: this wave's K-half producers, one 64B line.
  const unsigned* const fa = flags + (size_t)dir * NWG_DIR + kh * 16 + (lane & 15);

  for (int s = 0; s < T_LEN; ++s) {
    const int t = dir ? (T_LEN - 1 - s) : s;
    const bool hasNext = (s + 1 < T_LEN);

    f32x4 acc[3] = {{0.f,0.f,0.f,0.f},{0.f,0.f,0.f,0.f},{0.f,0.f,0.f,0.f}};

    if (!isHh) {
      half8 a[8];
      #pragma unroll
      for (int i = 0; i < 8; ++i) {
        float4 u = xn[2*i], w = xn[2*i+1];
        half8 h;
        h[0]=f2h(u.x); h[1]=f2h(u.y); h[2]=f2h(u.z); h[3]=f2h(u.w);
        h[4]=f2h(w.x); h[5]=f2h(w.y); h[6]=f2h(w.z); h[7]=f2h(w.w);
        a[i] = h;
      }
      #pragma unroll
      for (int i = 0; i < 8; ++i)
        #pragma unroll
        for (int gam = 0; gam < 3; ++gam)
          acc[gam] = __builtin_amdgcn_mfma_f32_16x16x32_f16(a[i], Bf[gam][i], acc[gam], 0, 0, 0);
    } else if (s > 0) {
      // ---- 2-deep pipelined flag poll (fan-in 16)
      {
        unsigned va, vb;
        asm volatile("global_load_dword %0, %1, off sc0 sc1" : "=&v"(va) : "v"(fa));
        asm volatile("global_load_dword %0, %1, off sc0 sc1" : "=&v"(vb) : "v"(fa));
        for (;;) {
          asm volatile("s_waitcnt vmcnt(1)" ::: "memory");
          if (__all(va >= (unsigned)s)) break;
          asm volatile("global_load_dword %0, %1, off sc0 sc1" : "=&v"(va) : "v"(fa));
          asm volatile("s_waitcnt vmcnt(1)" ::: "memory");
          if (__all(vb >= (unsigned)s)) break;
          asm volatile("global_load_dword %0, %1, off sc0 sc1" : "=&v"(vb) : "v"(fa));
        }
        asm volatile("s_waitcnt vmcnt(0)" ::: "memory");
      }
      // ---- load h(s-1) payload exactly once (early-clobber asm, proven)
      const char* p0 = (const char*)hexu
          + (((size_t)dir * 2 + ((s - 1) & 1)) * (B_SZ * (H_SZ / 2))) * 4
          + (size_t)arow * (H_SZ * 2) + (size_t)(kh * 256 + koff) * 2;
      int4v hv[8];
      asm volatile(
        "global_load_dwordx4 %0, %8, off sc0 sc1\n\t"
        "global_load_dwordx4 %1, %8, off offset:64 sc0 sc1\n\t"
        "global_load_dwordx4 %2, %8, off offset:128 sc0 sc1\n\t"
        "global_load_dwordx4 %3, %8, off offset:192 sc0 sc1\n\t"
        "global_load_dwordx4 %4, %8, off offset:256 sc0 sc1\n\t"
        "global_load_dwordx4 %5, %8, off offset:320 sc0 sc1\n\t"
        "global_load_dwordx4 %6, %8, off offset:384 sc0 sc1\n\t"
        "global_load_dwordx4 %7, %8, off offset:448 sc0 sc1\n\t"
        "s_waitcnt vmcnt(0)"
        : "=&v"(hv[0]), "=&v"(hv[1]), "=&v"(hv[2]), "=&v"(hv[3]),
          "=&v"(hv[4]), "=&v"(hv[5]), "=&v"(hv[6]), "=&v"(hv[7])
        : "v"(p0) : "memory");
      __builtin_amdgcn_sched_barrier(0);
      #pragma unroll
      for (int i = 0; i < 8; ++i) {
        half8 a = __builtin_bit_cast(half8, hv[i]);
        #pragma unroll
        for (int gam = 0; gam < 3; ++gam)
          acc[gam] = __builtin_amdgcn_mfma_f32_16x16x32_f16(a, Bf[gam][i], acc[gam], 0, 0, 0);
      }
    }
    // hh at s==0: acc stays zero (h0 = 0)

    // ---- write C-partials
    {
      const int src = isHh ? 1 : 0;
      #pragma unroll
      for (int gam = 0; gam < 3; ++gam) {
        float* cp = Cp + (size_t)(((src*2 + kh)*3 + gam)*2 + wm) * 272
                       + ((lane >> 4) << 2) * 17 + (lane & 15);
        #pragma unroll
        for (int vv2 = 0; vv2 < 4; ++vv2) cp[vv2 * 17] = acc[gam][vv2];
      }
    }
    bar_lgkm();   // B1: Cp ready (lgkm only)

    // ---- gates (all 512 threads): compute h(s), publish h pair
    float hnS;
    {
      const int mb = gb >> 4, rb = gb & 15;
      float sih[3], shh[3];
      #pragma unroll
      for (int gam = 0; gam < 3; ++gam) {
        float aih = 0.f, ahh = 0.f;
        #pragma unroll
        for (int q = 0; q < 2; ++q) {
          aih += Cp[(size_t)(((0*2+q)*3+gam)*2 + mb) * 272 + rb * 17 + gj];
          ahh += Cp[(size_t)(((1*2+q)*3+gam)*2 + mb) * 272 + rb * 17 + gj];
        }
        sih[gam] = aih + biasLds[gam * 16 + gj];
        shh[gam] = ahh + biasLds[48 + gam * 16 + gj];
      }
      const float r = sigm_f(sih[0] + shh[0]);
      const float z = sigm_f(sih[1] + shh[1]);
      const float n = tanh_f(sih[2] + r * shh[2]);
      const float hn = (1.f - z) * n + z * hreg;
      hreg = hn;
      hnS = hn;

      const float hother = __shfl_xor(hn, 1);
      if ((gj & 1) == 0) {
        union { unsigned u; _Float16 h[2]; } pr;
        pr.h[0] = f2h(hn); pr.h[1] = f2h(hother);
        unsigned* hp = hexu + ((size_t)dir * 2 + (s & 1)) * (B_SZ * (H_SZ / 2))
                     + (size_t)gb * (H_SZ / 2) + (g * JW + gj) / 2;
        __hip_atomic_store(hp, pr.u, __ATOMIC_RELAXED, __HIP_MEMORY_SCOPE_AGENT);
      }
    }
    // per-wave drain: only this step's h-store (+ long-landed older stores)
    asm volatile("s_waitcnt vmcnt(0)" ::: "memory");
    bar_lgkm();   // B2: every wave has drained its h-store
    if (tid == 0)
      __hip_atomic_store((unsigned*)&flags[(size_t)dir * NWG_DIR + g],
                         (unsigned)(s + 1),
                         __ATOMIC_RELAXED, __HIP_MEMORY_SCOPE_AGENT);

    // ---- off-chain tail: out stores, then issue x(t+1) prefetch
    out[((size_t)gb * T_LEN + t) * (2 * H_SZ) + dir * H_SZ + g * JW + gj] = hnS;
    if (s == T_LEN - 1) hlast[gb * H_SZ + g * JW + gj] = hnS;
    if (!isHh && hasNext) {
      const int tn = dir ? (T_LEN - 2 - s) : (s + 1);
      const float* base = xwavebase + (size_t)tn * D_SZ;
      #pragma unroll
      for (int i = 0; i < 8; ++i) {
        xn[2*i]   = *(const float4*)(base + i * 32);
        xn[2*i+1] = *(const float4*)(base + i * 32 + 4);
      }
    }
  }

  // signal heaters: this real WG is finished
  if (tid == 0)
    __hip_atomic_fetch_add(done, 1u, __ATOMIC_RELAXED, __HIP_MEMORY_SCOPE_AGENT);
}

extern "C" void kernel_launch(void* const* d_in, const int* in_sizes, int n_in,
                              void* d_out, int out_size, void* d_ws, size_t ws_size,
                              hipStream_t stream) {
  const float* x      = (const float*)d_in[0];
  const float* wih_fw = (const float*)d_in[1];
  const float* whh_fw = (const float*)d_in[2];
  const float* bih_fw = (const float*)d_in[3];
  const float* bhh_fw = (const float*)d_in[4];
  const float* wih_bw = (const float*)d_in[5];
  const float* whh_bw = (const float*)d_in[6];
  const float* bih_bw = (const float*)d_in[7];
  const float* bhh_bw = (const float*)d_in[8];
  float* out = (float*)d_out;

  // ws layout: [0..255] flags u32[2][32]; [256..259] done u32; pad to 512;
  //            [512..] hexu [2 dir][2 parity][32 rows][256 u32 pairs] = 128 KB.
  const size_t CTRL_BYTES = 512;
  const size_t HEX_BYTES  = (size_t)2 * 2 * B_SZ * (H_SZ / 2) * sizeof(unsigned);
  if (ws_size < CTRL_BYTES + HEX_BYTES) return;

  unsigned* flags = (unsigned*)d_ws;
  unsigned* done  = (unsigned*)((char*)d_ws + 256);
  unsigned* hexu  = (unsigned*)((char*)d_ws + CTRL_BYTES);

  hipMemsetAsync(d_ws, 0, CTRL_BYTES, stream);
  gru2_persistent<<<dim3(256), dim3(NTHR), 0, stream>>>(
      x, wih_fw, whh_fw, bih_fw, bhh_fw, wih_bw, whh_bw, bih_bw, bhh_bw,
      out, hexu, flags, done);
}

// Round 15
// 3925.072 us; speedup vs baseline: 1.2148x; 1.2148x over previous
//
#include <hip/hip_runtime.h>

// Bidirectional GRU, persistent-kernel. Round 15.
// Base: r13 VERBATIM (best, 4414us). Evidence for this round: FETCH_SIZE shows
// comm ops (sc0 sc1 relaxed-agent) are serviced memory-side (~784MB vs ~140MB
// algorithmic) -> RTT ~1us; r12/r14 killed SCLK+FCLK hypotheses; chain = 4
// such hops. Only remaining lever: XCD-local L2 comm (~300ns RTT).
// r10's replay corruption ROOT CAUSE: per-WG fence(ACQUIRE,agent)=buffer_inv
// on the SHARED XCD L2 at staggered times dropped other WGs' freshly-published
// dirty sc0 lines. FIX: grid barrier between ALL fences and FIRST sc0 publish.
// Exit release fence (wbl2) keeps dirty comm lines from overwriting the next
// replay's memset (lines left clean; next acquire re-fetches memset zeros).
// Liveness: every new spin budget-bounded (detection, grid barrier, fast
// polls) -> worst case fast absmax-fail, never a hang. Slow path = r13 exact.

#define T_LEN 1024
#define B_SZ  32
#define D_SZ  512
#define H_SZ  512
#define NWG_DIR 32
#define JW 16
#define NTHR 512

typedef __attribute__((ext_vector_type(8))) _Float16 half8;
typedef __attribute__((ext_vector_type(4))) float f32x4;
typedef __attribute__((ext_vector_type(4))) int int4v;

__device__ __forceinline__ _Float16 f2h(float f) { return (_Float16)f; }
__device__ __forceinline__ float sigm_f(float v) {
  return __builtin_amdgcn_rcpf(1.f + __expf(-v));
}
__device__ __forceinline__ float tanh_f(float v) {
  return 1.f - 2.f * __builtin_amdgcn_rcpf(1.f + __expf(2.f * v));
}
__device__ __forceinline__ void bar_lgkm() {
  asm volatile("s_waitcnt lgkmcnt(0)\ns_barrier" ::: "memory");
}

__global__ __launch_bounds__(NTHR, 2)
void gru2_persistent(const float* __restrict__ x,
                     const float* __restrict__ wih_fw, const float* __restrict__ whh_fw,
                     const float* __restrict__ bih_fw, const float* __restrict__ bhh_fw,
                     const float* __restrict__ wih_bw, const float* __restrict__ whh_bw,
                     const float* __restrict__ bih_bw, const float* __restrict__ bhh_bw,
                     float* __restrict__ out,
                     unsigned* __restrict__ hexu,
                     unsigned* __restrict__ flags,
                     unsigned* __restrict__ xcdmap,
                     unsigned* __restrict__ gbar)
{
  const int bid = blockIdx.x;
  const int dir = bid & 7;
  if (dir >= 2) return;            // 192 helper blocks exit
  const int g = bid >> 3;          // slice 0..31

  __shared__ float Cp[24 * 272];
  __shared__ float biasLds[96];
  __shared__ int fastSh;

  const int tid  = threadIdx.x;
  const int wave = tid >> 6;
  const int lane = tid & 63;

  const float* wih = dir ? wih_bw : wih_fw;
  const float* whh = dir ? whh_bw : whh_fw;
  const float* bih = dir ? bih_bw : bih_fw;
  const float* bhh = dir ? bhh_bw : bhh_fw;

  if (tid < 48) {
    int grow = (tid >> 4) * H_SZ + g * JW + (tid & 15);
    biasLds[tid]      = bih[grow];
    biasLds[48 + tid] = bhh[grow];
  }

  // ---- one-time XCD detection (LLC-scope atomics; budget-bounded) ----
  {
    unsigned xcc;
    asm volatile("s_getreg_b32 %0, hwreg(20, 0, 32)" : "=s"(xcc));  // XCC_ID
    if (tid == 0)
      __hip_atomic_store(&xcdmap[dir * NWG_DIR + g], xcc + 1u,
                         __ATOMIC_RELAXED, __HIP_MEMORY_SCOPE_AGENT);
    if (wave == 0) {
      unsigned v = 0u; int bud = 1 << 16; bool ok = true;
      for (;;) {
        v = __hip_atomic_load(&xcdmap[lane], __ATOMIC_RELAXED,
                              __HIP_MEMORY_SCOPE_AGENT);
        if (__all(v != 0u)) break;
        if (--bud < 0) { ok = false; break; }
        __builtin_amdgcn_s_sleep(8);
      }
      const unsigned ref0 = __shfl(v, 0);
      const unsigned ref1 = __shfl(v, NWG_DIR);
      const bool uni = __all((lane < NWG_DIR) ? (v == ref0) : (v == ref1));
      if (lane == 0) fastSh = (ok && uni && ref0 != ref1) ? 1 : 0;
    }
  }
  __syncthreads();
  const bool fast = (fastSh != 0);
  // acquire: drop stale clean L2 lines from the prior replay
  __builtin_amdgcn_fence(__ATOMIC_ACQUIRE, "agent");
  __syncthreads();   // every wave of this WG has fenced

  // ---- GRID BARRIER (the r10 fix): no sc0 publish until ALL 64 WGs fenced.
  if (tid == 0) {
    __hip_atomic_fetch_add(gbar, 1u, __ATOMIC_RELAXED, __HIP_MEMORY_SCOPE_AGENT);
    int bud = 1 << 20;
    while (__hip_atomic_load(gbar, __ATOMIC_RELAXED,
                             __HIP_MEMORY_SCOPE_AGENT) < 64u) {
      if (--bud < 0) break;
      __builtin_amdgcn_s_sleep(8);
    }
  }
  __syncthreads();

  const bool isHh = (wave >= 4);
  const int  wv   = wave & 3;
  const int  wm   = wv & 1;
  const int  kh   = wv >> 1;

  // ---- weight B-fragments in registers (layout proven r1-r14) ----
  half8 Bf[3][8];
  {
    const float* W = isHh ? whh : wih;
    #pragma unroll
    for (int gam = 0; gam < 3; ++gam) {
      const int row = gam * H_SZ + g * JW + (lane & 15);
      #pragma unroll
      for (int i = 0; i < 8; ++i) {
        const float* src = W + (size_t)row * D_SZ + (kh * 8 + i) * 32 + ((lane >> 4) << 3);
        float4 v0 = *(const float4*)(src);
        float4 v1 = *(const float4*)(src + 4);
        half8 b;
        b[0]=f2h(v0.x); b[1]=f2h(v0.y); b[2]=f2h(v0.z); b[3]=f2h(v0.w);
        b[4]=f2h(v1.x); b[5]=f2h(v1.y); b[6]=f2h(v1.z); b[7]=f2h(v1.w);
        Bf[gam][i] = b;
      }
    }
  }

  const int arow = wm * 16 + (lane & 15);
  const int koff = (lane >> 4) << 3;
  const float* const xwavebase = x + (size_t)arow * T_LEN * D_SZ + kh * 256 + koff;

  float4 xn[16];
  if (!isHh) {
    const int t0 = dir ? (T_LEN - 1) : 0;
    const float* base = xwavebase + (size_t)t0 * D_SZ;
    #pragma unroll
    for (int i = 0; i < 8; ++i) {
      xn[2*i]   = *(const float4*)(base + i * 32);
      xn[2*i+1] = *(const float4*)(base + i * 32 + 4);
    }
  }
  __syncthreads();

  float hreg = 0.f;
  const int gb = tid >> 4;
  const int gj = tid & 15;
  float* hlast = out + (size_t)B_SZ * T_LEN * (2 * H_SZ) + (size_t)dir * B_SZ * H_SZ;
  const unsigned* const fa = flags + (size_t)dir * NWG_DIR + kh * 16 + (lane & 15);
  int pollbud = 1 << 21;   // fast-path total poll budget (all steps)

  for (int s = 0; s < T_LEN; ++s) {
    const int t = dir ? (T_LEN - 1 - s) : s;
    const bool hasNext = (s + 1 < T_LEN);

    f32x4 acc[3] = {{0.f,0.f,0.f,0.f},{0.f,0.f,0.f,0.f},{0.f,0.f,0.f,0.f}};

    if (!isHh) {
      half8 a[8];
      #pragma unroll
      for (int i = 0; i < 8; ++i) {
        float4 u = xn[2*i], w = xn[2*i+1];
        half8 h;
        h[0]=f2h(u.x); h[1]=f2h(u.y); h[2]=f2h(u.z); h[3]=f2h(u.w);
        h[4]=f2h(w.x); h[5]=f2h(w.y); h[6]=f2h(w.z); h[7]=f2h(w.w);
        a[i] = h;
      }
      #pragma unroll
      for (int i = 0; i < 8; ++i)
        #pragma unroll
        for (int gam = 0; gam < 3; ++gam)
          acc[gam] = __builtin_amdgcn_mfma_f32_16x16x32_f16(a[i], Bf[gam][i], acc[gam], 0, 0, 0);
    } else if (s > 0) {
      if (fast) {
        // ---- fast poll: sc0 probes at XCD-L2 latency (budget-bounded)
        for (;;) {
          unsigned vv;
          asm volatile("global_load_dword %0, %1, off sc0\ns_waitcnt vmcnt(0)"
                       : "=&v"(vv) : "v"(fa) : "memory");
          if (__all(vv >= (unsigned)s)) break;
          if (--pollbud < 0) break;
        }
        const char* p0 = (const char*)hexu
            + (((size_t)dir * 2 + ((s - 1) & 1)) * (B_SZ * (H_SZ / 2))) * 4
            + (size_t)arow * (H_SZ * 2) + (size_t)(kh * 256 + koff) * 2;
        int4v hv[8];
        asm volatile(
          "global_load_dwordx4 %0, %8, off sc0\n\t"
          "global_load_dwordx4 %1, %8, off offset:64 sc0\n\t"
          "global_load_dwordx4 %2, %8, off offset:128 sc0\n\t"
          "global_load_dwordx4 %3, %8, off offset:192 sc0\n\t"
          "global_load_dwordx4 %4, %8, off offset:256 sc0\n\t"
          "global_load_dwordx4 %5, %8, off offset:320 sc0\n\t"
          "global_load_dwordx4 %6, %8, off offset:384 sc0\n\t"
          "global_load_dwordx4 %7, %8, off offset:448 sc0\n\t"
          "s_waitcnt vmcnt(0)"
          : "=&v"(hv[0]), "=&v"(hv[1]), "=&v"(hv[2]), "=&v"(hv[3]),
            "=&v"(hv[4]), "=&v"(hv[5]), "=&v"(hv[6]), "=&v"(hv[7])
          : "v"(p0) : "memory");
        __builtin_amdgcn_sched_barrier(0);
        #pragma unroll
        for (int i = 0; i < 8; ++i) {
          half8 a = __builtin_bit_cast(half8, hv[i]);
          #pragma unroll
          for (int gam = 0; gam < 3; ++gam)
            acc[gam] = __builtin_amdgcn_mfma_f32_16x16x32_f16(a, Bf[gam][i], acc[gam], 0, 0, 0);
        }
      } else {
        // ---- slow path: r13 exact (2-deep pipelined LLC poll + payload)
        {
          unsigned va, vb;
          asm volatile("global_load_dword %0, %1, off sc0 sc1" : "=&v"(va) : "v"(fa));
          asm volatile("global_load_dword %0, %1, off sc0 sc1" : "=&v"(vb) : "v"(fa));
          for (;;) {
            asm volatile("s_waitcnt vmcnt(1)" ::: "memory");
            if (__all(va >= (unsigned)s)) break;
            asm volatile("global_load_dword %0, %1, off sc0 sc1" : "=&v"(va) : "v"(fa));
            asm volatile("s_waitcnt vmcnt(1)" ::: "memory");
            if (__all(vb >= (unsigned)s)) break;
            asm volatile("global_load_dword %0, %1, off sc0 sc1" : "=&v"(vb) : "v"(fa));
          }
          asm volatile("s_waitcnt vmcnt(0)" ::: "memory");
        }
        const char* p0 = (const char*)hexu
            + (((size_t)dir * 2 + ((s - 1) & 1)) * (B_SZ * (H_SZ / 2))) * 4
            + (size_t)arow * (H_SZ * 2) + (size_t)(kh * 256 + koff) * 2;
        int4v hv[8];
        asm volatile(
          "global_load_dwordx4 %0, %8, off sc0 sc1\n\t"
          "global_load_dwordx4 %1, %8, off offset:64 sc0 sc1\n\t"
          "global_load_dwordx4 %2, %8, off offset:128 sc0 sc1\n\t"
          "global_load_dwordx4 %3, %8, off offset:192 sc0 sc1\n\t"
          "global_load_dwordx4 %4, %8, off offset:256 sc0 sc1\n\t"
          "global_load_dwordx4 %5, %8, off offset:320 sc0 sc1\n\t"
          "global_load_dwordx4 %6, %8, off offset:384 sc0 sc1\n\t"
          "global_load_dwordx4 %7, %8, off offset:448 sc0 sc1\n\t"
          "s_waitcnt vmcnt(0)"
          : "=&v"(hv[0]), "=&v"(hv[1]), "=&v"(hv[2]), "=&v"(hv[3]),
            "=&v"(hv[4]), "=&v"(hv[5]), "=&v"(hv[6]), "=&v"(hv[7])
          : "v"(p0) : "memory");
        __builtin_amdgcn_sched_barrier(0);
        #pragma unroll
        for (int i = 0; i < 8; ++i) {
          half8 a = __builtin_bit_cast(half8, hv[i]);
          #pragma unroll
          for (int gam = 0; gam < 3; ++gam)
            acc[gam] = __builtin_amdgcn_mfma_f32_16x16x32_f16(a, Bf[gam][i], acc[gam], 0, 0, 0);
        }
      }
    }

    // ---- write C-partials
    {
      const int src = isHh ? 1 : 0;
      #pragma unroll
      for (int gam = 0; gam < 3; ++gam) {
        float* cp = Cp + (size_t)(((src*2 + kh)*3 + gam)*2 + wm) * 272
                       + ((lane >> 4) << 2) * 17 + (lane & 15);
        #pragma unroll
        for (int vv2 = 0; vv2 < 4; ++vv2) cp[vv2 * 17] = acc[gam][vv2];
      }
    }
    bar_lgkm();   // B1

    // ---- gates: compute h(s), publish h pair
    float hnS;
    {
      const int mb = gb >> 4, rb = gb & 15;
      float sih[3], shh[3];
      #pragma unroll
      for (int gam = 0; gam < 3; ++gam) {
        float aih = 0.f, ahh = 0.f;
        #pragma unroll
        for (int q = 0; q < 2; ++q) {
          aih += Cp[(size_t)(((0*2+q)*3+gam)*2 + mb) * 272 + rb * 17 + gj];
          ahh += Cp[(size_t)(((1*2+q)*3+gam)*2 + mb) * 272 + rb * 17 + gj];
        }
        sih[gam] = aih + biasLds[gam * 16 + gj];
        shh[gam] = ahh + biasLds[48 + gam * 16 + gj];
      }
      const float r = sigm_f(sih[0] + shh[0]);
      const float z = sigm_f(sih[1] + shh[1]);
      const float n = tanh_f(sih[2] + r * shh[2]);
      const float hn = (1.f - z) * n + z * hreg;
      hreg = hn;
      hnS = hn;

      const float hother = __shfl_xor(hn, 1);
      if ((gj & 1) == 0) {
        union { unsigned u; _Float16 h[2]; } pr;
        pr.h[0] = f2h(hn); pr.h[1] = f2h(hother);
        unsigned* hp = hexu + ((size_t)dir * 2 + (s & 1)) * (B_SZ * (H_SZ / 2))
                     + (size_t)gb * (H_SZ / 2) + (g * JW + gj) / 2;
        if (fast)
          asm volatile("global_store_dword %0, %1, off sc0"
                       :: "v"(hp), "v"(pr.u) : "memory");
        else
          __hip_atomic_store(hp, pr.u, __ATOMIC_RELAXED, __HIP_MEMORY_SCOPE_AGENT);
      }
    }
    asm volatile("s_waitcnt vmcnt(0)" ::: "memory");  // h-store acked
    bar_lgkm();   // B2
    if (tid == 0) {
      unsigned* fp = flags + (size_t)dir * NWG_DIR + g;
      const unsigned fv = (unsigned)(s + 1);
      if (fast)
        asm volatile("global_store_dword %0, %1, off sc0"
                     :: "v"(fp), "v"(fv) : "memory");
      else
        __hip_atomic_store(fp, fv, __ATOMIC_RELAXED, __HIP_MEMORY_SCOPE_AGENT);
    }

    // ---- off-chain tail
    out[((size_t)gb * T_LEN + t) * (2 * H_SZ) + dir * H_SZ + g * JW + gj] = hnS;
    if (s == T_LEN - 1) hlast[gb * H_SZ + g * JW + gj] = hnS;
    if (!isHh && hasNext) {
      const int tn = dir ? (T_LEN - 2 - s) : (s + 1);
      const float* base = xwavebase + (size_t)tn * D_SZ;
      #pragma unroll
      for (int i = 0; i < 8; ++i) {
        xn[2*i]   = *(const float4*)(base + i * 32);
        xn[2*i+1] = *(const float4*)(base + i * 32 + 4);
      }
    }
  }

  // release: write back dirty comm lines (left clean) so the next replay's
  // memset+acquire sees sane state. Per-WG, after its own last sc0 store.
  __builtin_amdgcn_fence(__ATOMIC_RELEASE, "agent");
}

extern "C" void kernel_launch(void* const* d_in, const int* in_sizes, int n_in,
                              void* d_out, int out_size, void* d_ws, size_t ws_size,
                              hipStream_t stream) {
  const float* x      = (const float*)d_in[0];
  const float* wih_fw = (const float*)d_in[1];
  const float* whh_fw = (const float*)d_in[2];
  const float* bih_fw = (const float*)d_in[3];
  const float* bhh_fw = (const float*)d_in[4];
  const float* wih_bw = (const float*)d_in[5];
  const float* whh_bw = (const float*)d_in[6];
  const float* bih_bw = (const float*)d_in[7];
  const float* bhh_bw = (const float*)d_in[8];
  float* out = (float*)d_out;

  // ws: [0..255] xcdmap u32[64]; [256..511] flags u32[2][32]; [512..515] gbar;
  //     pad to 1024; then hexu [2][2][32][256] u32 = 128 KB.
  const size_t CTRL_BYTES = 1024;
  const size_t HEX_BYTES  = (size_t)2 * 2 * B_SZ * (H_SZ / 2) * sizeof(unsigned);
  if (ws_size < CTRL_BYTES + HEX_BYTES) return;

  unsigned* xcdmap = (unsigned*)d_ws;
  unsigned* flags  = (unsigned*)((char*)d_ws + 256);
  unsigned* gbar   = (unsigned*)((char*)d_ws + 512);
  unsigned* hexu   = (unsigned*)((char*)d_ws + CTRL_BYTES);

  hipMemsetAsync(d_ws, 0, CTRL_BYTES, stream);
  gru2_persistent<<<dim3(256), dim3(NTHR), 0, stream>>>(
      x, wih_fw, whh_fw, bih_fw, bhh_fw, wih_bw, whh_bw, bih_bw, bhh_bw,
      out, hexu, flags, xcdmap, gbar);
}